// Round 16
// baseline (1405.645 us; speedup 1.0000x reference)
//
#include <hip/hip_runtime.h>
#include <cstdint>
#include <cstddef>

#define T_TOK 8192
#define HDIM  2048
#define IDIM  4096
#define NEXP  8
#define MAXT  72   // sum_e ceil(cnt_e/256) <= 16384/256 + 7 = 71

typedef __bf16 bf16x8 __attribute__((ext_vector_type(8)));
typedef float  f32x4  __attribute__((ext_vector_type(4)));

#define BARRIER() __builtin_amdgcn_s_barrier()
#define LGKM0()   do { asm volatile("s_waitcnt lgkmcnt(0)" ::: "memory"); __builtin_amdgcn_sched_barrier(0); } while (0)
#define VMW(n)    do { asm volatile("s_waitcnt vmcnt(" #n ")" ::: "memory"); } while (0)
#define PRIO1()   __builtin_amdgcn_s_setprio(1)
#define PRIO0()   __builtin_amdgcn_s_setprio(0)

__device__ __forceinline__ unsigned short f2bf(float f) {
    union { float f; unsigned u; } v; v.f = f;
    unsigned r = v.u + 0x7FFFu + ((v.u >> 16) & 1u);   // RNE
    return (unsigned short)(r >> 16);
}

__device__ __forceinline__ void gload16(const void* g, void* l) {
    __builtin_amdgcn_global_load_lds((__attribute__((address_space(1))) void*)g,
                                     (__attribute__((address_space(3))) void*)l,
                                     16, 0, 0);
}

// ---------------- router (also emits hs_bf) ----------------
__global__ __launch_bounds__(256) void router_k(const float* __restrict__ hs,
                                                const float* __restrict__ rw,
                                                float* __restrict__ wgt,
                                                int* __restrict__ counts,
                                                int* __restrict__ lists,
                                                unsigned short* __restrict__ hs_bf) {
    int gid  = blockIdx.x * 256 + threadIdx.x;
    int tok  = gid >> 6;
    int lane = threadIdx.x & 63;
    const float* x = hs + (size_t)tok * HDIM;
    unsigned short* xb = hs_bf + (size_t)tok * HDIM;

    float acc[NEXP];
#pragma unroll
    for (int e = 0; e < NEXP; ++e) acc[e] = 0.f;
    for (int h = lane; h < HDIM; h += 64) {
        float xv = x[h];
        xb[h] = f2bf(xv);
#pragma unroll
        for (int e = 0; e < NEXP; ++e) acc[e] = fmaf(xv, rw[e * HDIM + h], acc[e]);
    }
#pragma unroll
    for (int off = 32; off > 0; off >>= 1) {
#pragma unroll
        for (int e = 0; e < NEXP; ++e) acc[e] += __shfl_xor(acc[e], off, 64);
    }
    if (lane == 0) {
        float m = acc[0];
#pragma unroll
        for (int e = 1; e < NEXP; ++e) m = fmaxf(m, acc[e]);
        float p[NEXP]; float s = 0.f;
#pragma unroll
        for (int e = 0; e < NEXP; ++e) { p[e] = expf(acc[e] - m); s += p[e]; }
        float inv = 1.f / s;
        int i1 = 0;
#pragma unroll
        for (int e = 1; e < NEXP; ++e) if (acc[e] > acc[i1]) i1 = e;
        int i2 = -1;
#pragma unroll
        for (int e = 0; e < NEXP; ++e) if (e != i1 && (i2 < 0 || acc[e] > acc[i2])) i2 = e;
#pragma unroll
        for (int e = 0; e < NEXP; ++e)
            wgt[(size_t)tok * NEXP + e] = (e == i1 || e == i2) ? p[e] * inv : 0.f;
        int p1 = atomicAdd(&counts[i1], 1);
        lists[i1 * T_TOK + p1] = tok;                 // slot 0
        int p2 = atomicAdd(&counts[i2], 1);
        lists[i2 * T_TOK + p2] = (1 << 16) | tok;     // slot 1
    }
}

// ---------------- planner (256-row granularity) ----------------
__global__ void plan_k(const int* __restrict__ counts, int* __restrict__ offs,
                       int* __restrict__ desc, int* __restrict__ ntiles) {
    if (threadIdx.x == 0 && blockIdx.x == 0) {
        int off = 0, n = 0;
        for (int e = 0; e < NEXP; ++e) {
            offs[e] = off;
            int nt = (counts[e] + 255) >> 8;
            for (int t = 0; t < nt; ++t) desc[n++] = (e << 16) | t;
            off += nt * 256;
        }
        *ntiles = n;
    }
}

// ---------------- fp32 -> bf16 ----------------
__global__ __launch_bounds__(256) void cvt_k(const float* __restrict__ in,
                                             unsigned short* __restrict__ out, long n4) {
    long i      = (long)blockIdx.x * 256 + threadIdx.x;
    long stride = (long)gridDim.x * 256;
    const float4* in4 = (const float4*)in;
    ushort4* out4 = (ushort4*)out;
    for (long j = i; j < n4; j += stride) {
        float4 v = in4[j];
        ushort4 o;
        o.x = f2bf(v.x); o.y = f2bf(v.y); o.z = f2bf(v.z); o.w = f2bf(v.w);
        out4[j] = o;
    }
}

// ============ GEMM1: fused gate/up, BM=256 BN=128+128, BK=64, 8 waves, 4-phase ============
// LDS 128 KiB: A [buf][4x8192] @0 ; Bg @65536+buf*16384 ; Bu @98304+buf*16384
// SINGLE VMW(4) per K-tile at P4-end: drains AH0/G/AH1/U of tile kt+1 exactly (ledger:
// outstanding oldest-first = AH0(kt+1),G(kt+1) [kt-1 P3/P4], AH1(kt+1) [P1], U(kt+1) [P2],
// AH0(kt+2) [P3], G(kt+2) [P4] = 12; VMW(4) drains first 8). All reads in next tile.
__global__ __launch_bounds__(512, 2) void gemm1_k(const unsigned short* __restrict__ A,
                                                  const unsigned short* __restrict__ Wall,
                                                  unsigned short* __restrict__ Hout,
                                                  const int* __restrict__ lists,
                                                  const int* __restrict__ counts,
                                                  const int* __restrict__ offs,
                                                  const int* __restrict__ desc,
                                                  const int* __restrict__ ntiles) {
    const int slot = blockIdx.y;
    if (slot >= *ntiles) return;
    const int dsc = desc[slot];
    const int e = dsc >> 16, tt = dsc & 0xFFFF;
    const int cnt = counts[e];
    const int t0 = tt * 256;
    const int* list = lists + e * T_TOK;
    const unsigned short* W = Wall + (size_t)e * 2 * IDIM * HDIM;
    const int hbase = offs[e];
    const int n0 = blockIdx.x * 128;

    extern __shared__ __align__(16) char lds[];

    const int tid  = threadIdx.x;
    const int lane = tid & 63;
    const int wid  = tid >> 6;
    const int wr   = wid >> 2;
    const int wc   = wid & 3;

    const int prow = tid >> 3;
    const int pcol = (tid & 7) * 16;
    const int lcol = (pcol ^ ((prow & 7) << 4)) >> 1;
    unsigned aoff[4];
#pragma unroll
    for (int i = 0; i < 4; ++i) {
        int g = t0 + i * 64 + prow;
        int tok = list[(g < cnt) ? g : t0] & 0xFFFF;
        aoff[i] = (unsigned)tok * HDIM + lcol;
    }
    unsigned goff[2], uoff[2];
#pragma unroll
    for (int i = 0; i < 2; ++i) {
        goff[i] = (unsigned)(n0 + i * 64 + prow) * HDIM + lcol;
        uoff[i] = (unsigned)(IDIM + n0 + i * 64 + prow) * HDIM + lcol;
    }
    const int dst = tid * 16;

#define SG_AH0(b, t) do { unsigned k0_ = (unsigned)((t) & 31) * 64;      \
    gload16(A + aoff[0] + k0_, lds + (b) * 32768 + dst);                 \
    gload16(A + aoff[1] + k0_, lds + (b) * 32768 + 8192 + dst); } while (0)
#define SG_AH1(b, t) do { unsigned k0_ = (unsigned)((t) & 31) * 64;      \
    gload16(A + aoff[2] + k0_, lds + (b) * 32768 + 16384 + dst);         \
    gload16(A + aoff[3] + k0_, lds + (b) * 32768 + 24576 + dst); } while (0)
#define SG_G(b, t) do { unsigned k0_ = (unsigned)((t) & 31) * 64;        \
    gload16(W + goff[0] + k0_, lds + 65536 + (b) * 16384 + dst);         \
    gload16(W + goff[1] + k0_, lds + 65536 + (b) * 16384 + 8192 + dst); } while (0)
#define SG_U(b, t) do { unsigned k0_ = (unsigned)((t) & 31) * 64;        \
    gload16(W + uoff[0] + k0_, lds + 98304 + (b) * 16384 + dst);         \
    gload16(W + uoff[1] + k0_, lds + 98304 + (b) * 16384 + 8192 + dst); } while (0)

    const int frd = (lane & 7) << 4;
    const int cb0 = (((lane >> 4) * 16)     ) ^ frd;
    const int cb1 = (((lane >> 4) * 16) | 64) ^ frd;
    const int arow = (wr * 64 + (lane & 15)) * 128;
    const int brow = (wc * 32 + (lane & 15)) * 128;

    f32x4 accg[8][2], accu[8][2];
#pragma unroll
    for (int mi = 0; mi < 8; ++mi)
#pragma unroll
        for (int ni = 0; ni < 2; ++ni) {
            accg[mi][ni] = (f32x4){0.f, 0.f, 0.f, 0.f};
            accu[mi][ni] = (f32x4){0.f, 0.f, 0.f, 0.f};
        }

    // prologue: tile0 full (8 loads, drained) + tile1 AH0/G (4, left in flight)
    SG_AH0(0, 0); SG_G(0, 0); SG_U(0, 0); SG_AH1(0, 0);
    SG_AH0(1, 1); SG_G(1, 1);
    VMW(4);
    BARRIER();

    const int NT = HDIM / 64;   // 32
    for (int kt = 0; kt < NT; ++kt) {
        const int b  = kt & 1;
        const int bn = b ^ 1;
        const char* la = lds + b * 32768 + arow;
        const char* lg = lds + 65536 + b * 16384 + brow;
        const char* lu = lds + 98304 + b * 16384 + brow;
        bf16x8 a0[2][4], bg[2][2], bu[2][2];

        // P1: reads A-h0 + Bg; stage AH1(kt+1)
#pragma unroll
        for (int mi = 0; mi < 4; ++mi) {
            a0[0][mi] = *(const bf16x8*)(la + mi * 2048 + cb0);
            a0[1][mi] = *(const bf16x8*)(la + mi * 2048 + cb1);
        }
#pragma unroll
        for (int ni = 0; ni < 2; ++ni) {
            bg[0][ni] = *(const bf16x8*)(lg + ni * 2048 + cb0);
            bg[1][ni] = *(const bf16x8*)(lg + ni * 2048 + cb1);
        }
        SG_AH1(bn, kt + 1);
        BARRIER(); LGKM0(); PRIO1();
#pragma unroll
        for (int ks = 0; ks < 2; ++ks)
#pragma unroll
            for (int mi = 0; mi < 4; ++mi)
#pragma unroll
                for (int ni = 0; ni < 2; ++ni)
                    accg[mi][ni] = __builtin_amdgcn_mfma_f32_16x16x32_bf16(a0[ks][mi], bg[ks][ni], accg[mi][ni], 0, 0, 0);
        PRIO0(); BARRIER();

        // P2: reads Bu; stage U(kt+1)
#pragma unroll
        for (int ni = 0; ni < 2; ++ni) {
            bu[0][ni] = *(const bf16x8*)(lu + ni * 2048 + cb0);
            bu[1][ni] = *(const bf16x8*)(lu + ni * 2048 + cb1);
        }
        SG_U(bn, kt + 1);
        BARRIER(); LGKM0(); PRIO1();
#pragma unroll
        for (int ks = 0; ks < 2; ++ks)
#pragma unroll
            for (int mi = 0; mi < 4; ++mi)
#pragma unroll
                for (int ni = 0; ni < 2; ++ni)
                    accu[mi][ni] = __builtin_amdgcn_mfma_f32_16x16x32_bf16(a0[ks][mi], bu[ks][ni], accu[mi][ni], 0, 0, 0);
        PRIO0(); BARRIER();

        // P3: reads A-h1 (bg reused); stage AH0(kt+2)
#pragma unroll
        for (int mi = 0; mi < 4; ++mi) {
            a0[0][mi] = *(const bf16x8*)(la + 16384 + mi * 2048 + cb0);
            a0[1][mi] = *(const bf16x8*)(la + 16384 + mi * 2048 + cb1);
        }
        SG_AH0(b, kt + 2);
        BARRIER(); LGKM0(); PRIO1();
#pragma unroll
        for (int ks = 0; ks < 2; ++ks)
#pragma unroll
            for (int mi = 0; mi < 4; ++mi)
#pragma unroll
                for (int ni = 0; ni < 2; ++ni)
                    accg[mi + 4][ni] = __builtin_amdgcn_mfma_f32_16x16x32_bf16(a0[ks][mi], bg[ks][ni], accg[mi + 4][ni], 0, 0, 0);
        PRIO0(); BARRIER();

        // P4: 0 reads; stage G(kt+2); single per-tile drain VMW(4)
        SG_G(b, kt + 2);
        PRIO1();
#pragma unroll
        for (int ks = 0; ks < 2; ++ks)
#pragma unroll
            for (int mi = 0; mi < 4; ++mi)
#pragma unroll
                for (int ni = 0; ni < 2; ++ni)
                    accu[mi + 4][ni] = __builtin_amdgcn_mfma_f32_16x16x32_bf16(a0[ks][mi], bu[ks][ni], accu[mi + 4][ni], 0, 0, 0);
        PRIO0();
        VMW(4);
        BARRIER();
    }
    VMW(0);
#undef SG_AH0
#undef SG_AH1
#undef SG_G
#undef SG_U

#pragma unroll
    for (int mi = 0; mi < 8; ++mi)
#pragma unroll
        for (int ni = 0; ni < 2; ++ni)
#pragma unroll
            for (int j = 0; j < 4; ++j) {
                int qr = mi >> 2, m = mi & 3;
                int row = hbase + t0 + qr * 128 + wr * 64 + m * 16 + ((lane >> 4) << 2) + j;
                int col = n0 + wc * 32 + ni * 16 + (lane & 15);
                float g = accg[mi][ni][j], u = accu[mi][ni][j];
                float hv = (g / (1.f + expf(-g))) * u;
                Hout[(size_t)row * IDIM + col] = f2bf(hv);
            }
}

// ============ GEMM2: BM=128 (z-half of 256-slot) x BN=256, BK=64, 8 waves, 2-phase ============
// LDS 96 KiB: A [buf][16KB] @0 ; B [buf][32KB] @32768
// Ledger: P1 stages BH1(kt+1); P2 stages A(kt+2)+BH0(kt+2); single VMW(4) at P2-end drains
// A/BH0/BH1 of tile kt+1 (oldest 6 of 10). A/BH0 reads occur only in P1 (regs reused in P2),
// so P2's stages are WAR-safe via the P1-end barrier.
__global__ __launch_bounds__(512, 2) void gemm2_k(const unsigned short* __restrict__ Ah,
                                                  const unsigned short* __restrict__ Ball,
                                                  const float* __restrict__ wgt,
                                                  float* __restrict__ outP,
                                                  const int* __restrict__ lists,
                                                  const int* __restrict__ counts,
                                                  const int* __restrict__ offs,
                                                  const int* __restrict__ desc,
                                                  const int* __restrict__ ntiles) {
    const int slot = blockIdx.y;
    if (slot >= *ntiles) return;
    const int dsc = desc[slot];
    const int e = dsc >> 16, tt = dsc & 0xFFFF;
    const int cnt = counts[e];
    const int t0 = tt * 256 + blockIdx.z * 128;     // 128-row half-tile
    if (t0 >= cnt) return;
    const int* list = lists + e * T_TOK;
    const unsigned short* B = Ball + (size_t)e * HDIM * IDIM;
    const int hbase = offs[e];
    const int n0 = blockIdx.x * 256;

    extern __shared__ __align__(16) char lds[];

    const int tid  = threadIdx.x;
    const int lane = tid & 63;
    const int wid  = tid >> 6;
    const int wr   = wid >> 2;   // 64-row band (0..1)
    const int wc   = wid & 3;    // 64-col band

    const int prow = tid >> 3;
    const int pcol = (tid & 7) * 16;
    const int lcol = (pcol ^ ((prow & 7) << 4)) >> 1;
    unsigned aoff[2], boff[4];
#pragma unroll
    for (int i = 0; i < 2; ++i)
        aoff[i] = (unsigned)(hbase + t0 + i * 64 + prow) * IDIM + lcol;
#pragma unroll
    for (int i = 0; i < 4; ++i)
        boff[i] = (unsigned)(n0 + i * 64 + prow) * IDIM + lcol;
    const int dst = tid * 16;

#define SG_A(b, t) do { unsigned k0_ = (unsigned)((t) & 63) * 64;         \
    gload16(Ah + aoff[0] + k0_, lds + (b) * 16384 + dst);                 \
    gload16(Ah + aoff[1] + k0_, lds + (b) * 16384 + 8192 + dst); } while (0)
#define SG_BH0(b, t) do { unsigned k0_ = (unsigned)((t) & 63) * 64;       \
    gload16(B + boff[0] + k0_, lds + 32768 + (b) * 32768 + dst);          \
    gload16(B + boff[1] + k0_, lds + 32768 + (b) * 32768 + 8192 + dst); } while (0)
#define SG_BH1(b, t) do { unsigned k0_ = (unsigned)((t) & 63) * 64;       \
    gload16(B + boff[2] + k0_, lds + 32768 + (b) * 32768 + 16384 + dst);  \
    gload16(B + boff[3] + k0_, lds + 32768 + (b) * 32768 + 24576 + dst); } while (0)

    const int frd = (lane & 7) << 4;
    const int cb0 = (((lane >> 4) * 16)     ) ^ frd;
    const int cb1 = (((lane >> 4) * 16) | 64) ^ frd;
    const int arow = (wr * 64 + (lane & 15)) * 128;   // + mi*2048 + b*16384
    const int brow = (wc * 64 + (lane & 15)) * 128;   // + ni*2048 + 32768 + b*32768

    f32x4 acc[4][4];
#pragma unroll
    for (int mi = 0; mi < 4; ++mi)
#pragma unroll
        for (int ni = 0; ni < 4; ++ni) acc[mi][ni] = (f32x4){0.f, 0.f, 0.f, 0.f};

    // prologue: tile0 full (6 loads, drained) + tile1 A/BH0 (4, in flight)
    SG_A(0, 0); SG_BH0(0, 0); SG_BH1(0, 0);
    SG_A(1, 1); SG_BH0(1, 1);
    VMW(4);
    BARRIER();

    const int NT = IDIM / 64;   // 64
    for (int kt = 0; kt < NT; ++kt) {
        const int b  = kt & 1;
        const int bn = b ^ 1;
        const char* la = lds + b * 16384 + arow;
        const char* lb = lds + 32768 + b * 32768 + brow;
        bf16x8 a0[2][4], bb[2][4];

        // P1: reads A (8) + B ni0-1 (4); stage BH1(kt+1); MFMA ni0-1
#pragma unroll
        for (int mi = 0; mi < 4; ++mi) {
            a0[0][mi] = *(const bf16x8*)(la + mi * 2048 + cb0);
            a0[1][mi] = *(const bf16x8*)(la + mi * 2048 + cb1);
        }
#pragma unroll
        for (int ni = 0; ni < 2; ++ni) {
            bb[0][ni] = *(const bf16x8*)(lb + ni * 2048 + cb0);
            bb[1][ni] = *(const bf16x8*)(lb + ni * 2048 + cb1);
        }
        SG_BH1(bn, kt + 1);
        BARRIER(); LGKM0(); PRIO1();
#pragma unroll
        for (int ks = 0; ks < 2; ++ks)
#pragma unroll
            for (int mi = 0; mi < 4; ++mi)
#pragma unroll
                for (int ni = 0; ni < 2; ++ni)
                    acc[mi][ni] = __builtin_amdgcn_mfma_f32_16x16x32_bf16(a0[ks][mi], bb[ks][ni], acc[mi][ni], 0, 0, 0);
        PRIO0(); BARRIER();

        // P2: reads B ni2-3 (4); stage A(kt+2)+BH0(kt+2); MFMA ni2-3; VMW(4)
#pragma unroll
        for (int ni = 0; ni < 2; ++ni) {
            bb[0][ni + 2] = *(const bf16x8*)(lb + (ni + 2) * 2048 + cb0);
            bb[1][ni + 2] = *(const bf16x8*)(lb + (ni + 2) * 2048 + cb1);
        }
        SG_A(b, kt + 2);
        SG_BH0(b, kt + 2);
        BARRIER(); LGKM0(); PRIO1();
#pragma unroll
        for (int ks = 0; ks < 2; ++ks)
#pragma unroll
            for (int mi = 0; mi < 4; ++mi)
#pragma unroll
                for (int ni = 0; ni < 2; ++ni)
                    acc[mi][ni + 2] = __builtin_amdgcn_mfma_f32_16x16x32_bf16(a0[ks][mi], bb[ks][ni + 2], acc[mi][ni + 2], 0, 0, 0);
        PRIO0();
        VMW(4);   // drains A/BH0/BH1 of tile kt+1; leaves A/BH0(kt+2) in flight
        BARRIER();
    }
    VMW(0);
#undef SG_A
#undef SG_BH0
#undef SG_BH1

#pragma unroll
    for (int mi = 0; mi < 4; ++mi) {
#pragma unroll
        for (int j = 0; j < 4; ++j) {
            int g = t0 + wr * 64 + mi * 16 + ((lane >> 4) << 2) + j;
            if (g < cnt) {
                int ent = list[g];
                int tok = ent & 0xFFFF;
                int sl  = ent >> 16;
                float w = wgt[(size_t)tok * NEXP + e];
                float* o = outP + (size_t)sl * T_TOK * HDIM + (size_t)tok * HDIM;
#pragma unroll
                for (int ni = 0; ni < 4; ++ni) {
                    int col = n0 + wc * 64 + ni * 16 + (lane & 15);
                    o[col] = w * acc[mi][ni][j];
                }
            }
        }
    }
}

// ---------------- combine ----------------
__global__ __launch_bounds__(256) void combine_k(const float* __restrict__ p0,
                                                 const float* __restrict__ p1,
                                                 float* __restrict__ out, long n4) {
    long i      = (long)blockIdx.x * 256 + threadIdx.x;
    long stride = (long)gridDim.x * 256;
    const float4* a4 = (const float4*)p0;
    const float4* b4 = (const float4*)p1;
    float4* o4 = (float4*)out;
    for (long j = i; j < n4; j += stride) {
        float4 a = a4[j], b = b4[j];
        o4[j] = make_float4(a.x + b.x, a.y + b.y, a.z + b.z, a.w + b.w);
    }
}

extern "C" void kernel_launch(void* const* d_in, const int* in_sizes, int n_in,
                              void* d_out, int out_size, void* d_ws, size_t ws_size,
                              hipStream_t stream) {
    const float* hs  = (const float*)d_in[0];
    const float* rw  = (const float*)d_in[1];
    const float* ws  = (const float*)d_in[2];
    const float* w2s = (const float*)d_in[3];
    float* out = (float*)d_out;

    char* wsp = (char*)d_ws;
    unsigned short* hs_bf = (unsigned short*)(wsp);                 //  33,554,432
    unsigned short* w_bf  = (unsigned short*)(wsp + 33554432ULL);   // 268,435,456
    unsigned short* w2_bf = (unsigned short*)(wsp + 301989888ULL);  // 134,217,728
    unsigned short* h_bf  = (unsigned short*)(wsp + 436207616ULL);  // 150,994,944 (18432 x IDIM)
    float*          outP  = (float*)(wsp + 587202560ULL);           // 134,217,728
    float*          wgt   = (float*)(wsp + 721420288ULL);           //     262,144
    int*            counts = (int*)(wsp + 721682432ULL);
    int*            offs   = (int*)(wsp + 721682560ULL);
    int*            lists  = (int*)(wsp + 721682688ULL);            //     262,144
    int*            desc   = (int*)(wsp + 721944832ULL);            //         512
    int*            ntiles = (int*)(wsp + 721945344ULL);

    hipMemsetAsync(counts, 0, NEXP * sizeof(int), stream);
    cvt_k<<<4096, 256, 0, stream>>>(ws, w_bf, (long)NEXP * 2 * IDIM * HDIM / 4);
    cvt_k<<<4096, 256, 0, stream>>>(w2s, w2_bf, (long)NEXP * HDIM * IDIM / 4);
    router_k<<<(T_TOK * 64) / 256, 256, 0, stream>>>(hs, rw, wgt, counts, lists, hs_bf);
    plan_k<<<1, 64, 0, stream>>>(counts, offs, desc, ntiles);

    gemm1_k<<<dim3(IDIM / 128, MAXT), 512, 131072, stream>>>(
        hs_bf, w_bf, h_bf, lists, counts, offs, desc, ntiles);
    gemm2_k<<<dim3(HDIM / 256, MAXT, 2), 512, 98304, stream>>>(
        h_bf, w2_bf, wgt, outP, lists, counts, offs, desc, ntiles);
    combine_k<<<2048, 256, 0, stream>>>(outP, outP + (size_t)T_TOK * HDIM, out,
                                        (long)T_TOK * HDIM / 4);
}

// Round 17
// 1367.955 us; speedup vs baseline: 1.0276x; 1.0276x over previous
//
#include <hip/hip_runtime.h>
#include <cstdint>
#include <cstddef>

#define T_TOK 8192
#define HDIM  2048
#define IDIM  4096
#define NEXP  8
#define MAXT  72   // sum_e ceil(cnt_e/256) <= 16384/256 + 7 = 71

typedef __bf16 bf16x8 __attribute__((ext_vector_type(8)));
typedef float  f32x4  __attribute__((ext_vector_type(4)));

#define BARRIER() __builtin_amdgcn_s_barrier()
#define VMW(n)    do { asm volatile("s_waitcnt vmcnt(" #n ")" ::: "memory"); } while (0)
#define PRIO1()   __builtin_amdgcn_s_setprio(1)
#define PRIO0()   __builtin_amdgcn_s_setprio(0)

__device__ __forceinline__ unsigned short f2bf(float f) {
    union { float f; unsigned u; } v; v.f = f;
    unsigned r = v.u + 0x7FFFu + ((v.u >> 16) & 1u);   // RNE
    return (unsigned short)(r >> 16);
}

__device__ __forceinline__ void gload16(const void* g, void* l) {
    __builtin_amdgcn_global_load_lds((__attribute__((address_space(1))) void*)g,
                                     (__attribute__((address_space(3))) void*)l,
                                     16, 0, 0);
}

// ---------------- router (also emits hs_bf) ----------------
__global__ __launch_bounds__(256) void router_k(const float* __restrict__ hs,
                                                const float* __restrict__ rw,
                                                float* __restrict__ wgt,
                                                int* __restrict__ counts,
                                                int* __restrict__ lists,
                                                unsigned short* __restrict__ hs_bf) {
    int gid  = blockIdx.x * 256 + threadIdx.x;
    int tok  = gid >> 6;
    int lane = threadIdx.x & 63;
    const float* x = hs + (size_t)tok * HDIM;
    unsigned short* xb = hs_bf + (size_t)tok * HDIM;

    float acc[NEXP];
#pragma unroll
    for (int e = 0; e < NEXP; ++e) acc[e] = 0.f;
    for (int h = lane; h < HDIM; h += 64) {
        float xv = x[h];
        xb[h] = f2bf(xv);
#pragma unroll
        for (int e = 0; e < NEXP; ++e) acc[e] = fmaf(xv, rw[e * HDIM + h], acc[e]);
    }
#pragma unroll
    for (int off = 32; off > 0; off >>= 1) {
#pragma unroll
        for (int e = 0; e < NEXP; ++e) acc[e] += __shfl_xor(acc[e], off, 64);
    }
    if (lane == 0) {
        float m = acc[0];
#pragma unroll
        for (int e = 1; e < NEXP; ++e) m = fmaxf(m, acc[e]);
        float p[NEXP]; float s = 0.f;
#pragma unroll
        for (int e = 0; e < NEXP; ++e) { p[e] = expf(acc[e] - m); s += p[e]; }
        float inv = 1.f / s;
        int i1 = 0;
#pragma unroll
        for (int e = 1; e < NEXP; ++e) if (acc[e] > acc[i1]) i1 = e;
        int i2 = -1;
#pragma unroll
        for (int e = 0; e < NEXP; ++e) if (e != i1 && (i2 < 0 || acc[e] > acc[i2])) i2 = e;
#pragma unroll
        for (int e = 0; e < NEXP; ++e)
            wgt[(size_t)tok * NEXP + e] = (e == i1 || e == i2) ? p[e] * inv : 0.f;
        int p1 = atomicAdd(&counts[i1], 1);
        lists[i1 * T_TOK + p1] = tok;                 // slot 0
        int p2 = atomicAdd(&counts[i2], 1);
        lists[i2 * T_TOK + p2] = (1 << 16) | tok;     // slot 1
    }
}

// ---------------- planner (256-row granularity) ----------------
__global__ void plan_k(const int* __restrict__ counts, int* __restrict__ offs,
                       int* __restrict__ desc, int* __restrict__ ntiles) {
    if (threadIdx.x == 0 && blockIdx.x == 0) {
        int off = 0, n = 0;
        for (int e = 0; e < NEXP; ++e) {
            offs[e] = off;
            int nt = (counts[e] + 255) >> 8;
            for (int t = 0; t < nt; ++t) desc[n++] = (e << 16) | t;
            off += nt * 256;
        }
        *ntiles = n;
    }
}

// ---------------- fp32 -> bf16 ----------------
__global__ __launch_bounds__(256) void cvt_k(const float* __restrict__ in,
                                             unsigned short* __restrict__ out, long n4) {
    long i      = (long)blockIdx.x * 256 + threadIdx.x;
    long stride = (long)gridDim.x * 256;
    const float4* in4 = (const float4*)in;
    ushort4* out4 = (ushort4*)out;
    for (long j = i; j < n4; j += stride) {
        float4 v = in4[j];
        ushort4 o;
        o.x = f2bf(v.x); o.y = f2bf(v.y); o.z = f2bf(v.z); o.w = f2bf(v.w);
        out4[j] = o;
    }
}

// ============ GEMM1: fused gate/up, BM=256 BN=128+128, BK=64, 8 waves, 4-phase ============
// LDS 128 KiB: A [buf][4x8192] @0 ; Bg @65536+buf*16384 ; Bu @98304+buf*16384
// Single VMW(4)/K-tile at P4-end (ledger as r16). No explicit lgkmcnt: ds_read->MFMA deps
// are compiler-visible -> hipcc emits fine-grained lgkmcnt(N) (m97 evidence); no sched pin.
__global__ __launch_bounds__(512, 2) void gemm1_k(const unsigned short* __restrict__ A,
                                                  const unsigned short* __restrict__ Wall,
                                                  unsigned short* __restrict__ Hout,
                                                  const int* __restrict__ lists,
                                                  const int* __restrict__ counts,
                                                  const int* __restrict__ offs,
                                                  const int* __restrict__ desc,
                                                  const int* __restrict__ ntiles) {
    const int slot = blockIdx.y;
    if (slot >= *ntiles) return;
    const int dsc = desc[slot];
    const int e = dsc >> 16, tt = dsc & 0xFFFF;
    const int cnt = counts[e];
    const int t0 = tt * 256;
    const int* list = lists + e * T_TOK;
    const unsigned short* W = Wall + (size_t)e * 2 * IDIM * HDIM;
    const int hbase = offs[e];
    const int n0 = blockIdx.x * 128;

    extern __shared__ __align__(16) char lds[];

    const int tid  = threadIdx.x;
    const int lane = tid & 63;
    const int wid  = tid >> 6;
    const int wr   = wid >> 2;
    const int wc   = wid & 3;

    const int prow = tid >> 3;
    const int pcol = (tid & 7) * 16;
    const int lcol = (pcol ^ ((prow & 7) << 4)) >> 1;
    unsigned aoff[4];
#pragma unroll
    for (int i = 0; i < 4; ++i) {
        int g = t0 + i * 64 + prow;
        int tok = list[(g < cnt) ? g : t0] & 0xFFFF;
        aoff[i] = (unsigned)tok * HDIM + lcol;
    }
    unsigned goff[2], uoff[2];
#pragma unroll
    for (int i = 0; i < 2; ++i) {
        goff[i] = (unsigned)(n0 + i * 64 + prow) * HDIM + lcol;
        uoff[i] = (unsigned)(IDIM + n0 + i * 64 + prow) * HDIM + lcol;
    }
    const int dst = tid * 16;

#define SG_AH0(b, t) do { unsigned k0_ = (unsigned)((t) & 31) * 64;      \
    gload16(A + aoff[0] + k0_, lds + (b) * 32768 + dst);                 \
    gload16(A + aoff[1] + k0_, lds + (b) * 32768 + 8192 + dst); } while (0)
#define SG_AH1(b, t) do { unsigned k0_ = (unsigned)((t) & 31) * 64;      \
    gload16(A + aoff[2] + k0_, lds + (b) * 32768 + 16384 + dst);         \
    gload16(A + aoff[3] + k0_, lds + (b) * 32768 + 24576 + dst); } while (0)
#define SG_G(b, t) do { unsigned k0_ = (unsigned)((t) & 31) * 64;        \
    gload16(W + goff[0] + k0_, lds + 65536 + (b) * 16384 + dst);         \
    gload16(W + goff[1] + k0_, lds + 65536 + (b) * 16384 + 8192 + dst); } while (0)
#define SG_U(b, t) do { unsigned k0_ = (unsigned)((t) & 31) * 64;        \
    gload16(W + uoff[0] + k0_, lds + 98304 + (b) * 16384 + dst);         \
    gload16(W + uoff[1] + k0_, lds + 98304 + (b) * 16384 + 8192 + dst); } while (0)

    const int frd = (lane & 7) << 4;
    const int cb0 = (((lane >> 4) * 16)     ) ^ frd;
    const int cb1 = (((lane >> 4) * 16) | 64) ^ frd;
    const int arow = (wr * 64 + (lane & 15)) * 128;
    const int brow = (wc * 32 + (lane & 15)) * 128;

    f32x4 accg[8][2], accu[8][2];
#pragma unroll
    for (int mi = 0; mi < 8; ++mi)
#pragma unroll
        for (int ni = 0; ni < 2; ++ni) {
            accg[mi][ni] = (f32x4){0.f, 0.f, 0.f, 0.f};
            accu[mi][ni] = (f32x4){0.f, 0.f, 0.f, 0.f};
        }

    // prologue: tile0 full (8 loads, drained) + tile1 AH0/G (4, left in flight)
    SG_AH0(0, 0); SG_G(0, 0); SG_U(0, 0); SG_AH1(0, 0);
    SG_AH0(1, 1); SG_G(1, 1);
    VMW(4);
    BARRIER();

    const int NT = HDIM / 64;   // 32
    for (int kt = 0; kt < NT; ++kt) {
        const int b  = kt & 1;
        const int bn = b ^ 1;
        const char* la = lds + b * 32768 + arow;
        const char* lg = lds + 65536 + b * 16384 + brow;
        const char* lu = lds + 98304 + b * 16384 + brow;
        bf16x8 a0[2][4], bg[2][2], bu[2][2];

        // P1: reads A-h0 + Bg; stage AH1(kt+1)
#pragma unroll
        for (int mi = 0; mi < 4; ++mi) {
            a0[0][mi] = *(const bf16x8*)(la + mi * 2048 + cb0);
            a0[1][mi] = *(const bf16x8*)(la + mi * 2048 + cb1);
        }
#pragma unroll
        for (int ni = 0; ni < 2; ++ni) {
            bg[0][ni] = *(const bf16x8*)(lg + ni * 2048 + cb0);
            bg[1][ni] = *(const bf16x8*)(lg + ni * 2048 + cb1);
        }
        SG_AH1(bn, kt + 1);
        BARRIER(); PRIO1();
#pragma unroll
        for (int ks = 0; ks < 2; ++ks)
#pragma unroll
            for (int mi = 0; mi < 4; ++mi)
#pragma unroll
                for (int ni = 0; ni < 2; ++ni)
                    accg[mi][ni] = __builtin_amdgcn_mfma_f32_16x16x32_bf16(a0[ks][mi], bg[ks][ni], accg[mi][ni], 0, 0, 0);
        PRIO0(); BARRIER();

        // P2: reads Bu; stage U(kt+1)
#pragma unroll
        for (int ni = 0; ni < 2; ++ni) {
            bu[0][ni] = *(const bf16x8*)(lu + ni * 2048 + cb0);
            bu[1][ni] = *(const bf16x8*)(lu + ni * 2048 + cb1);
        }
        SG_U(bn, kt + 1);
        BARRIER(); PRIO1();
#pragma unroll
        for (int ks = 0; ks < 2; ++ks)
#pragma unroll
            for (int mi = 0; mi < 4; ++mi)
#pragma unroll
                for (int ni = 0; ni < 2; ++ni)
                    accu[mi][ni] = __builtin_amdgcn_mfma_f32_16x16x32_bf16(a0[ks][mi], bu[ks][ni], accu[mi][ni], 0, 0, 0);
        PRIO0(); BARRIER();

        // P3: reads A-h1 (bg reused); stage AH0(kt+2)
#pragma unroll
        for (int mi = 0; mi < 4; ++mi) {
            a0[0][mi] = *(const bf16x8*)(la + 16384 + mi * 2048 + cb0);
            a0[1][mi] = *(const bf16x8*)(la + 16384 + mi * 2048 + cb1);
        }
        SG_AH0(b, kt + 2);
        BARRIER(); PRIO1();
#pragma unroll
        for (int ks = 0; ks < 2; ++ks)
#pragma unroll
            for (int mi = 0; mi < 4; ++mi)
#pragma unroll
                for (int ni = 0; ni < 2; ++ni)
                    accg[mi + 4][ni] = __builtin_amdgcn_mfma_f32_16x16x32_bf16(a0[ks][mi], bg[ks][ni], accg[mi + 4][ni], 0, 0, 0);
        PRIO0(); BARRIER();

        // P4: 0 reads; stage G(kt+2); single per-tile drain VMW(4)
        SG_G(b, kt + 2);
        PRIO1();
#pragma unroll
        for (int ks = 0; ks < 2; ++ks)
#pragma unroll
            for (int mi = 0; mi < 4; ++mi)
#pragma unroll
                for (int ni = 0; ni < 2; ++ni)
                    accu[mi + 4][ni] = __builtin_amdgcn_mfma_f32_16x16x32_bf16(a0[ks][mi], bu[ks][ni], accu[mi + 4][ni], 0, 0, 0);
        PRIO0();
        VMW(4);
        BARRIER();
    }
    VMW(0);
#undef SG_AH0
#undef SG_AH1
#undef SG_G
#undef SG_U

#pragma unroll
    for (int mi = 0; mi < 8; ++mi)
#pragma unroll
        for (int ni = 0; ni < 2; ++ni)
#pragma unroll
            for (int j = 0; j < 4; ++j) {
                int qr = mi >> 2, m = mi & 3;
                int row = hbase + t0 + qr * 128 + wr * 64 + m * 16 + ((lane >> 4) << 2) + j;
                int col = n0 + wc * 32 + ni * 16 + (lane & 15);
                float g = accg[mi][ni][j], u = accu[mi][ni][j];
                float hv = (g / (1.f + expf(-g))) * u;
                Hout[(size_t)row * IDIM + col] = f2bf(hv);
            }
}

// ============ GEMM2 (r13 proven, lgkm0 removed): BM=256 BN=256 BK=64, 8 waves, 4-phase ============
// LDS 128 KiB: A [buf][4x8192] @0 ; B [buf][4x8192] @65536
// Stage groups: AH1@P1, BH1@P2, AH0@P3(kt+2), BH0@P4(kt+2); single VMW(4)+barrier at P4-end.
__global__ __launch_bounds__(512, 2) void gemm2_k(const unsigned short* __restrict__ Ah,
                                                  const unsigned short* __restrict__ Ball,
                                                  const float* __restrict__ wgt,
                                                  float* __restrict__ outP,
                                                  const int* __restrict__ lists,
                                                  const int* __restrict__ counts,
                                                  const int* __restrict__ offs,
                                                  const int* __restrict__ desc,
                                                  const int* __restrict__ ntiles) {
    const int slot = blockIdx.y;
    if (slot >= *ntiles) return;
    const int dsc = desc[slot];
    const int e = dsc >> 16, tt = dsc & 0xFFFF;
    const int cnt = counts[e];
    const int t0 = tt * 256;
    const int* list = lists + e * T_TOK;
    const unsigned short* B = Ball + (size_t)e * HDIM * IDIM;
    const int hbase = offs[e];
    const int n0 = blockIdx.x * 256;

    extern __shared__ __align__(16) char lds[];

    const int tid  = threadIdx.x;
    const int lane = tid & 63;
    const int wid  = tid >> 6;
    const int wr   = wid >> 2;
    const int wc   = wid & 3;

    const int prow = tid >> 3;
    const int pcol = (tid & 7) * 16;
    const int lcol = (pcol ^ ((prow & 7) << 4)) >> 1;
    unsigned aoff[4], boff[4];
#pragma unroll
    for (int i = 0; i < 4; ++i) {
        aoff[i] = (unsigned)(hbase + t0 + i * 64 + prow) * IDIM + lcol;
        boff[i] = (unsigned)(n0 + i * 64 + prow) * IDIM + lcol;
    }
    const int dst = tid * 16;

#define SG_AH0(b, t) do { unsigned k0_ = (unsigned)((t) & 63) * 64;       \
    gload16(Ah + aoff[0] + k0_, lds + (b) * 32768 + dst);                 \
    gload16(Ah + aoff[1] + k0_, lds + (b) * 32768 + 8192 + dst); } while (0)
#define SG_AH1(b, t) do { unsigned k0_ = (unsigned)((t) & 63) * 64;       \
    gload16(Ah + aoff[2] + k0_, lds + (b) * 32768 + 16384 + dst);         \
    gload16(Ah + aoff[3] + k0_, lds + (b) * 32768 + 24576 + dst); } while (0)
#define SG_BH0(b, t) do { unsigned k0_ = (unsigned)((t) & 63) * 64;       \
    gload16(B + boff[0] + k0_, lds + 65536 + (b) * 32768 + dst);          \
    gload16(B + boff[1] + k0_, lds + 65536 + (b) * 32768 + 8192 + dst); } while (0)
#define SG_BH1(b, t) do { unsigned k0_ = (unsigned)((t) & 63) * 64;       \
    gload16(B + boff[2] + k0_, lds + 65536 + (b) * 32768 + 16384 + dst);  \
    gload16(B + boff[3] + k0_, lds + 65536 + (b) * 32768 + 24576 + dst); } while (0)

    const int frd = (lane & 7) << 4;
    const int cb0 = (((lane >> 4) * 16)     ) ^ frd;
    const int cb1 = (((lane >> 4) * 16) | 64) ^ frd;
    const int arow = (wr * 64 + (lane & 15)) * 128;
    const int brow = (wc * 64 + (lane & 15)) * 128;

    f32x4 acc[8][4];
#pragma unroll
    for (int mi = 0; mi < 8; ++mi)
#pragma unroll
        for (int ni = 0; ni < 4; ++ni) acc[mi][ni] = (f32x4){0.f, 0.f, 0.f, 0.f};

    SG_AH0(0, 0); SG_BH0(0, 0); SG_AH1(0, 0); SG_BH1(0, 0);
    SG_AH0(1, 1); SG_BH0(1, 1);
    VMW(0);
    BARRIER();

    const int NT = IDIM / 64;   // 64
    for (int kt = 0; kt < NT; ++kt) {
        const int b  = kt & 1;
        const int bn = b ^ 1;
        const char* la = lds + b * 32768 + arow;
        const char* lb = lds + 65536 + b * 32768 + brow;
        bf16x8 a0[2][4], bb[2][4];

        // P1: reads A-h0 + B ni0-1; stage AH1(kt+1)
#pragma unroll
        for (int mi = 0; mi < 4; ++mi) {
            a0[0][mi] = *(const bf16x8*)(la + mi * 2048 + cb0);
            a0[1][mi] = *(const bf16x8*)(la + mi * 2048 + cb1);
        }
#pragma unroll
        for (int ni = 0; ni < 2; ++ni) {
            bb[0][ni] = *(const bf16x8*)(lb + ni * 2048 + cb0);
            bb[1][ni] = *(const bf16x8*)(lb + ni * 2048 + cb1);
        }
        SG_AH1(bn, kt + 1);
        BARRIER(); PRIO1();
#pragma unroll
        for (int ks = 0; ks < 2; ++ks)
#pragma unroll
            for (int mi = 0; mi < 4; ++mi)
#pragma unroll
                for (int ni = 0; ni < 2; ++ni)
                    acc[mi][ni] = __builtin_amdgcn_mfma_f32_16x16x32_bf16(a0[ks][mi], bb[ks][ni], acc[mi][ni], 0, 0, 0);
        PRIO0(); BARRIER();

        // P2: reads B ni2-3; stage BH1(kt+1)
#pragma unroll
        for (int ni = 0; ni < 2; ++ni) {
            bb[0][ni + 2] = *(const bf16x8*)(lb + (ni + 2) * 2048 + cb0);
            bb[1][ni + 2] = *(const bf16x8*)(lb + (ni + 2) * 2048 + cb1);
        }
        SG_BH1(bn, kt + 1);
        BARRIER(); PRIO1();
#pragma unroll
        for (int ks = 0; ks < 2; ++ks)
#pragma unroll
            for (int mi = 0; mi < 4; ++mi)
#pragma unroll
                for (int ni = 0; ni < 2; ++ni)
                    acc[mi][ni + 2] = __builtin_amdgcn_mfma_f32_16x16x32_bf16(a0[ks][mi], bb[ks][ni + 2], acc[mi][ni + 2], 0, 0, 0);
        PRIO0(); BARRIER();

        // P3: reads A-h1 (bb reused); stage AH0(kt+2)
#pragma unroll
        for (int mi = 0; mi < 4; ++mi) {
            a0[0][mi] = *(const bf16x8*)(la + 16384 + mi * 2048 + cb0);
            a0[1][mi] = *(const bf16x8*)(la + 16384 + mi * 2048 + cb1);
        }
        SG_AH0(b, kt + 2);
        BARRIER(); PRIO1();
#pragma unroll
        for (int ks = 0; ks < 2; ++ks)
#pragma unroll
            for (int mi = 0; mi < 4; ++mi)
#pragma unroll
                for (int ni = 0; ni < 2; ++ni)
                    acc[mi + 4][ni] = __builtin_amdgcn_mfma_f32_16x16x32_bf16(a0[ks][mi], bb[ks][ni], acc[mi + 4][ni], 0, 0, 0);
        PRIO0(); BARRIER();

        // P4: 0 reads; stage BH0(kt+2); end VMW(4)
        SG_BH0(b, kt + 2);
        PRIO1();
#pragma unroll
        for (int ks = 0; ks < 2; ++ks)
#pragma unroll
            for (int mi = 0; mi < 4; ++mi)
#pragma unroll
                for (int ni = 0; ni < 2; ++ni)
                    acc[mi + 4][ni + 2] = __builtin_amdgcn_mfma_f32_16x16x32_bf16(a0[ks][mi], bb[ks][ni + 2], acc[mi + 4][ni + 2], 0, 0, 0);
        PRIO0();
        VMW(4);
        BARRIER();
    }
    VMW(0);
#undef SG_AH0
#undef SG_AH1
#undef SG_BH0
#undef SG_BH1

#pragma unroll
    for (int mi = 0; mi < 8; ++mi) {
        int qr = mi >> 2, m = mi & 3;
#pragma unroll
        for (int j = 0; j < 4; ++j) {
            int g = t0 + qr * 128 + wr * 64 + m * 16 + ((lane >> 4) << 2) + j;
            if (g < cnt) {
                int ent = list[g];
                int tok = ent & 0xFFFF;
                int sl  = ent >> 16;
                float w = wgt[(size_t)tok * NEXP + e];
                float* o = outP + (size_t)sl * T_TOK * HDIM + (size_t)tok * HDIM;
#pragma unroll
                for (int ni = 0; ni < 4; ++ni) {
                    int col = n0 + wc * 64 + ni * 16 + (lane & 15);
                    o[col] = w * acc[mi][ni][j];
                }
            }
        }
    }
}

// ---------------- combine ----------------
__global__ __launch_bounds__(256) void combine_k(const float* __restrict__ p0,
                                                 const float* __restrict__ p1,
                                                 float* __restrict__ out, long n4) {
    long i      = (long)blockIdx.x * 256 + threadIdx.x;
    long stride = (long)gridDim.x * 256;
    const float4* a4 = (const float4*)p0;
    const float4* b4 = (const float4*)p1;
    float4* o4 = (float4*)out;
    for (long j = i; j < n4; j += stride) {
        float4 a = a4[j], b = b4[j];
        o4[j] = make_float4(a.x + b.x, a.y + b.y, a.z + b.z, a.w + b.w);
    }
}

extern "C" void kernel_launch(void* const* d_in, const int* in_sizes, int n_in,
                              void* d_out, int out_size, void* d_ws, size_t ws_size,
                              hipStream_t stream) {
    const float* hs  = (const float*)d_in[0];
    const float* rw  = (const float*)d_in[1];
    const float* ws  = (const float*)d_in[2];
    const float* w2s = (const float*)d_in[3];
    float* out = (float*)d_out;

    char* wsp = (char*)d_ws;
    unsigned short* hs_bf = (unsigned short*)(wsp);                 //  33,554,432
    unsigned short* w_bf  = (unsigned short*)(wsp + 33554432ULL);   // 268,435,456
    unsigned short* w2_bf = (unsigned short*)(wsp + 301989888ULL);  // 134,217,728
    unsigned short* h_bf  = (unsigned short*)(wsp + 436207616ULL);  // 150,994,944 (18432 x IDIM)
    float*          outP  = (float*)(wsp + 587202560ULL);           // 134,217,728
    float*          wgt   = (float*)(wsp + 721420288ULL);           //     262,144
    int*            counts = (int*)(wsp + 721682432ULL);
    int*            offs   = (int*)(wsp + 721682560ULL);
    int*            lists  = (int*)(wsp + 721682688ULL);            //     262,144
    int*            desc   = (int*)(wsp + 721944832ULL);            //         512
    int*            ntiles = (int*)(wsp + 721945344ULL);

    hipMemsetAsync(counts, 0, NEXP * sizeof(int), stream);
    cvt_k<<<4096, 256, 0, stream>>>(ws, w_bf, (long)NEXP * 2 * IDIM * HDIM / 4);
    cvt_k<<<4096, 256, 0, stream>>>(w2s, w2_bf, (long)NEXP * HDIM * IDIM / 4);
    router_k<<<(T_TOK * 64) / 256, 256, 0, stream>>>(hs, rw, wgt, counts, lists, hs_bf);
    plan_k<<<1, 64, 0, stream>>>(counts, offs, desc, ntiles);

    gemm1_k<<<dim3(IDIM / 128, MAXT), 512, 131072, stream>>>(
        hs_bf, w_bf, h_bf, lists, counts, offs, desc, ntiles);
    gemm2_k<<<dim3(HDIM / 256, MAXT), 512, 131072, stream>>>(
        h_bf, w2_bf, wgt, outP, lists, counts, offs, desc, ntiles);
    combine_k<<<2048, 256, 0, stream>>>(outP, outP + (size_t)T_TOK * HDIM, out,
                                        (long)T_TOK * HDIM / 4);
}

// Round 18
// 1347.234 us; speedup vs baseline: 1.0434x; 1.0154x over previous
//
#include <hip/hip_runtime.h>
#include <cstdint>
#include <cstddef>

#define T_TOK 8192
#define HDIM  2048
#define IDIM  4096
#define NEXP  8
#define MAXT  72   // sum_e ceil(cnt_e/256) <= 16384/256 + 7 = 71

typedef __bf16 bf16x8 __attribute__((ext_vector_type(8)));
typedef float  f32x4  __attribute__((ext_vector_type(4)));

#define BARRIER() __builtin_amdgcn_s_barrier()
#define VMW(n)    do { asm volatile("s_waitcnt vmcnt(" #n ")" ::: "memory"); } while (0)
#define PRIO1()   __builtin_amdgcn_s_setprio(1)
#define PRIO0()   __builtin_amdgcn_s_setprio(0)

__device__ __forceinline__ unsigned short f2bf(float f) {
    union { float f; unsigned u; } v; v.f = f;
    unsigned r = v.u + 0x7FFFu + ((v.u >> 16) & 1u);   // RNE
    return (unsigned short)(r >> 16);
}

__device__ __forceinline__ void gload16(const void* g, void* l) {
    __builtin_amdgcn_global_load_lds((__attribute__((address_space(1))) void*)g,
                                     (__attribute__((address_space(3))) void*)l,
                                     16, 0, 0);
}

// ---------------- router (also emits hs_bf) ----------------
__global__ __launch_bounds__(256) void router_k(const float* __restrict__ hs,
                                                const float* __restrict__ rw,
                                                float* __restrict__ wgt,
                                                int* __restrict__ counts,
                                                int* __restrict__ lists,
                                                unsigned short* __restrict__ hs_bf) {
    int gid  = blockIdx.x * 256 + threadIdx.x;
    int tok  = gid >> 6;
    int lane = threadIdx.x & 63;
    const float* x = hs + (size_t)tok * HDIM;
    unsigned short* xb = hs_bf + (size_t)tok * HDIM;

    float acc[NEXP];
#pragma unroll
    for (int e = 0; e < NEXP; ++e) acc[e] = 0.f;
    for (int h = lane; h < HDIM; h += 64) {
        float xv = x[h];
        xb[h] = f2bf(xv);
#pragma unroll
        for (int e = 0; e < NEXP; ++e) acc[e] = fmaf(xv, rw[e * HDIM + h], acc[e]);
    }
#pragma unroll
    for (int off = 32; off > 0; off >>= 1) {
#pragma unroll
        for (int e = 0; e < NEXP; ++e) acc[e] += __shfl_xor(acc[e], off, 64);
    }
    if (lane == 0) {
        float m = acc[0];
#pragma unroll
        for (int e = 1; e < NEXP; ++e) m = fmaxf(m, acc[e]);
        float p[NEXP]; float s = 0.f;
#pragma unroll
        for (int e = 0; e < NEXP; ++e) { p[e] = expf(acc[e] - m); s += p[e]; }
        float inv = 1.f / s;
        int i1 = 0;
#pragma unroll
        for (int e = 1; e < NEXP; ++e) if (acc[e] > acc[i1]) i1 = e;
        int i2 = -1;
#pragma unroll
        for (int e = 0; e < NEXP; ++e) if (e != i1 && (i2 < 0 || acc[e] > acc[i2])) i2 = e;
#pragma unroll
        for (int e = 0; e < NEXP; ++e)
            wgt[(size_t)tok * NEXP + e] = (e == i1 || e == i2) ? p[e] * inv : 0.f;
        int p1 = atomicAdd(&counts[i1], 1);
        lists[i1 * T_TOK + p1] = tok;                 // slot 0
        int p2 = atomicAdd(&counts[i2], 1);
        lists[i2 * T_TOK + p2] = (1 << 16) | tok;     // slot 1
    }
}

// ---------------- planner (256-row granularity) ----------------
__global__ void plan_k(const int* __restrict__ counts, int* __restrict__ offs,
                       int* __restrict__ desc, int* __restrict__ ntiles) {
    if (threadIdx.x == 0 && blockIdx.x == 0) {
        int off = 0, n = 0;
        for (int e = 0; e < NEXP; ++e) {
            offs[e] = off;
            int nt = (counts[e] + 255) >> 8;
            for (int t = 0; t < nt; ++t) desc[n++] = (e << 16) | t;
            off += nt * 256;
        }
        *ntiles = n;
    }
}

// ---------------- fp32 -> bf16 ----------------
__global__ __launch_bounds__(256) void cvt_k(const float* __restrict__ in,
                                             unsigned short* __restrict__ out, long n4) {
    long i      = (long)blockIdx.x * 256 + threadIdx.x;
    long stride = (long)gridDim.x * 256;
    const float4* in4 = (const float4*)in;
    ushort4* out4 = (ushort4*)out;
    for (long j = i; j < n4; j += stride) {
        float4 v = in4[j];
        ushort4 o;
        o.x = f2bf(v.x); o.y = f2bf(v.y); o.z = f2bf(v.z); o.w = f2bf(v.w);
        out4[j] = o;
    }
}

// ============ GEMM1: fused gate/up, BM=256 BN=128+128, BK=64, 8 waves, 4-phase ============
// LDS 128 KiB: A [buf][4x8192] @0 ; Bg @65536+buf*16384 ; Bu @98304+buf*16384
// READ-AHEAD schedule: phase p issues ds_reads for phase p+1, so the LDS port is served
// under phase p's MFMA. Per-tile VMW(4) mid-P4 (ledger: outstanding=12, drains all of kt+1),
// then barrier, then next-P1 pre-reads. WAR pairs all separated by >=2 barriers (see notes).
__global__ __launch_bounds__(512, 2) void gemm1_k(const unsigned short* __restrict__ A,
                                                  const unsigned short* __restrict__ Wall,
                                                  unsigned short* __restrict__ Hout,
                                                  const int* __restrict__ lists,
                                                  const int* __restrict__ counts,
                                                  const int* __restrict__ offs,
                                                  const int* __restrict__ desc,
                                                  const int* __restrict__ ntiles) {
    const int slot = blockIdx.y;
    if (slot >= *ntiles) return;
    const int dsc = desc[slot];
    const int e = dsc >> 16, tt = dsc & 0xFFFF;
    const int cnt = counts[e];
    const int t0 = tt * 256;
    const int* list = lists + e * T_TOK;
    const unsigned short* W = Wall + (size_t)e * 2 * IDIM * HDIM;
    const int hbase = offs[e];
    const int n0 = blockIdx.x * 128;

    extern __shared__ __align__(16) char lds[];

    const int tid  = threadIdx.x;
    const int lane = tid & 63;
    const int wid  = tid >> 6;
    const int wr   = wid >> 2;
    const int wc   = wid & 3;

    const int prow = tid >> 3;
    const int pcol = (tid & 7) * 16;
    const int lcol = (pcol ^ ((prow & 7) << 4)) >> 1;
    unsigned aoff[4];
#pragma unroll
    for (int i = 0; i < 4; ++i) {
        int g = t0 + i * 64 + prow;
        int tok = list[(g < cnt) ? g : t0] & 0xFFFF;
        aoff[i] = (unsigned)tok * HDIM + lcol;
    }
    unsigned goff[2], uoff[2];
#pragma unroll
    for (int i = 0; i < 2; ++i) {
        goff[i] = (unsigned)(n0 + i * 64 + prow) * HDIM + lcol;
        uoff[i] = (unsigned)(IDIM + n0 + i * 64 + prow) * HDIM + lcol;
    }
    const int dst = tid * 16;

#define SG_AH0(b, t) do { unsigned k0_ = (unsigned)((t) & 31) * 64;      \
    gload16(A + aoff[0] + k0_, lds + (b) * 32768 + dst);                 \
    gload16(A + aoff[1] + k0_, lds + (b) * 32768 + 8192 + dst); } while (0)
#define SG_AH1(b, t) do { unsigned k0_ = (unsigned)((t) & 31) * 64;      \
    gload16(A + aoff[2] + k0_, lds + (b) * 32768 + 16384 + dst);         \
    gload16(A + aoff[3] + k0_, lds + (b) * 32768 + 24576 + dst); } while (0)
#define SG_G(b, t) do { unsigned k0_ = (unsigned)((t) & 31) * 64;        \
    gload16(W + goff[0] + k0_, lds + 65536 + (b) * 16384 + dst);         \
    gload16(W + goff[1] + k0_, lds + 65536 + (b) * 16384 + 8192 + dst); } while (0)
#define SG_U(b, t) do { unsigned k0_ = (unsigned)((t) & 31) * 64;        \
    gload16(W + uoff[0] + k0_, lds + 98304 + (b) * 16384 + dst);         \
    gload16(W + uoff[1] + k0_, lds + 98304 + (b) * 16384 + 8192 + dst); } while (0)

    const int frd = (lane & 7) << 4;
    const int cb0 = (((lane >> 4) * 16)     ) ^ frd;
    const int cb1 = (((lane >> 4) * 16) | 64) ^ frd;
    const int arow = (wr * 64 + (lane & 15)) * 128;
    const int brow = (wc * 32 + (lane & 15)) * 128;

    f32x4 accg[8][2], accu[8][2];
#pragma unroll
    for (int mi = 0; mi < 8; ++mi)
#pragma unroll
        for (int ni = 0; ni < 2; ++ni) {
            accg[mi][ni] = (f32x4){0.f, 0.f, 0.f, 0.f};
            accu[mi][ni] = (f32x4){0.f, 0.f, 0.f, 0.f};
        }

    // prologue: tile0 full (drained) + tile1 AH0/G (in flight); pre-read P1 regs (a0,bg)
    SG_AH0(0, 0); SG_G(0, 0); SG_U(0, 0); SG_AH1(0, 0);
    SG_AH0(1, 1); SG_G(1, 1);
    VMW(4);
    BARRIER();

    bf16x8 a0[2][4], a1[2][4], bg[2][2], bu[2][2];
    {
        const char* la = lds + arow;
        const char* lg = lds + 65536 + brow;
#pragma unroll
        for (int mi = 0; mi < 4; ++mi) {
            a0[0][mi] = *(const bf16x8*)(la + mi * 2048 + cb0);
            a0[1][mi] = *(const bf16x8*)(la + mi * 2048 + cb1);
        }
#pragma unroll
        for (int ni = 0; ni < 2; ++ni) {
            bg[0][ni] = *(const bf16x8*)(lg + ni * 2048 + cb0);
            bg[1][ni] = *(const bf16x8*)(lg + ni * 2048 + cb1);
        }
    }

    const int NT = HDIM / 64;   // 32
    for (int kt = 0; kt < NT; ++kt) {
        const int b  = kt & 1;
        const int bn = b ^ 1;
        const char* la  = lds + b * 32768 + arow;
        const char* lu  = lds + 98304 + b * 16384 + brow;
        const char* lan = lds + bn * 32768 + arow;
        const char* lgn = lds + 65536 + bn * 16384 + brow;

        // ---- P1: pre-read bu(b) [for P2]; stage AH1(kt+1); MFMA gate-qr0 (a0,bg) ----
#pragma unroll
        for (int ni = 0; ni < 2; ++ni) {
            bu[0][ni] = *(const bf16x8*)(lu + ni * 2048 + cb0);
            bu[1][ni] = *(const bf16x8*)(lu + ni * 2048 + cb1);
        }
        SG_AH1(bn, kt + 1);
        PRIO1();
#pragma unroll
        for (int ks = 0; ks < 2; ++ks)
#pragma unroll
            for (int mi = 0; mi < 4; ++mi)
#pragma unroll
                for (int ni = 0; ni < 2; ++ni)
                    accg[mi][ni] = __builtin_amdgcn_mfma_f32_16x16x32_bf16(a0[ks][mi], bg[ks][ni], accg[mi][ni], 0, 0, 0);
        PRIO0(); BARRIER();

        // ---- P2: pre-read a1(b) [for P3]; stage U(kt+1); MFMA up-qr0 (a0,bu) ----
#pragma unroll
        for (int mi = 0; mi < 4; ++mi) {
            a1[0][mi] = *(const bf16x8*)(la + 16384 + mi * 2048 + cb0);
            a1[1][mi] = *(const bf16x8*)(la + 16384 + mi * 2048 + cb1);
        }
        SG_U(bn, kt + 1);
        PRIO1();
#pragma unroll
        for (int ks = 0; ks < 2; ++ks)
#pragma unroll
            for (int mi = 0; mi < 4; ++mi)
#pragma unroll
                for (int ni = 0; ni < 2; ++ni)
                    accu[mi][ni] = __builtin_amdgcn_mfma_f32_16x16x32_bf16(a0[ks][mi], bu[ks][ni], accu[mi][ni], 0, 0, 0);
        PRIO0(); BARRIER();

        // ---- P3: stage AH0(kt+2); MFMA gate-qr1 (a1,bg) ----
        SG_AH0(b, kt + 2);
        PRIO1();
#pragma unroll
        for (int ks = 0; ks < 2; ++ks)
#pragma unroll
            for (int mi = 0; mi < 4; ++mi)
#pragma unroll
                for (int ni = 0; ni < 2; ++ni)
                    accg[mi + 4][ni] = __builtin_amdgcn_mfma_f32_16x16x32_bf16(a1[ks][mi], bg[ks][ni], accg[mi + 4][ni], 0, 0, 0);
        PRIO0(); BARRIER();

        // ---- P4: stage G(kt+2); VMW(4) drains kt+1; BAR; pre-read next a0/bg(bn); MFMA up-qr1 ----
        SG_G(b, kt + 2);
        VMW(4);
        BARRIER();
#pragma unroll
        for (int mi = 0; mi < 4; ++mi) {
            a0[0][mi] = *(const bf16x8*)(lan + mi * 2048 + cb0);
            a0[1][mi] = *(const bf16x8*)(lan + mi * 2048 + cb1);
        }
#pragma unroll
        for (int ni = 0; ni < 2; ++ni) {
            bg[0][ni] = *(const bf16x8*)(lgn + ni * 2048 + cb0);
            bg[1][ni] = *(const bf16x8*)(lgn + ni * 2048 + cb1);
        }
        PRIO1();
#pragma unroll
        for (int ks = 0; ks < 2; ++ks)
#pragma unroll
            for (int mi = 0; mi < 4; ++mi)
#pragma unroll
                for (int ni = 0; ni < 2; ++ni)
                    accu[mi + 4][ni] = __builtin_amdgcn_mfma_f32_16x16x32_bf16(a1[ks][mi], bu[ks][ni], accu[mi + 4][ni], 0, 0, 0);
        PRIO0();
        BARRIER();
    }
    VMW(0);
#undef SG_AH0
#undef SG_AH1
#undef SG_G
#undef SG_U

#pragma unroll
    for (int mi = 0; mi < 8; ++mi)
#pragma unroll
        for (int ni = 0; ni < 2; ++ni)
#pragma unroll
            for (int j = 0; j < 4; ++j) {
                int qr = mi >> 2, m = mi & 3;
                int row = hbase + t0 + qr * 128 + wr * 64 + m * 16 + ((lane >> 4) << 2) + j;
                int col = n0 + wc * 32 + ni * 16 + (lane & 15);
                float g = accg[mi][ni][j], u = accu[mi][ni][j];
                float hv = (g / (1.f + expf(-g))) * u;
                Hout[(size_t)row * IDIM + col] = f2bf(hv);
            }
}

// ============ GEMM2: BM=256 BN=256 BK=64, 8 waves, 4-phase, READ-AHEAD, scatter epilogue ============
// LDS 128 KiB: A [buf][4x8192] @0 ; B [buf][4x8192] @65536
// Phases: P1 (a0 x b01, pre-read b23), P2 (a0 x b23, pre-read a1), P3 (a1 x b01),
// P4 (stage BH0; VMW(4); BAR; pre-read next a0/b01; a1 x b23).
__global__ __launch_bounds__(512, 2) void gemm2_k(const unsigned short* __restrict__ Ah,
                                                  const unsigned short* __restrict__ Ball,
                                                  const float* __restrict__ wgt,
                                                  float* __restrict__ outP,
                                                  const int* __restrict__ lists,
                                                  const int* __restrict__ counts,
                                                  const int* __restrict__ offs,
                                                  const int* __restrict__ desc,
                                                  const int* __restrict__ ntiles) {
    const int slot = blockIdx.y;
    if (slot >= *ntiles) return;
    const int dsc = desc[slot];
    const int e = dsc >> 16, tt = dsc & 0xFFFF;
    const int cnt = counts[e];
    const int t0 = tt * 256;
    const int* list = lists + e * T_TOK;
    const unsigned short* B = Ball + (size_t)e * HDIM * IDIM;
    const int hbase = offs[e];
    const int n0 = blockIdx.x * 256;

    extern __shared__ __align__(16) char lds[];

    const int tid  = threadIdx.x;
    const int lane = tid & 63;
    const int wid  = tid >> 6;
    const int wr   = wid >> 2;
    const int wc   = wid & 3;

    const int prow = tid >> 3;
    const int pcol = (tid & 7) * 16;
    const int lcol = (pcol ^ ((prow & 7) << 4)) >> 1;
    unsigned aoff[4], boff[4];
#pragma unroll
    for (int i = 0; i < 4; ++i) {
        aoff[i] = (unsigned)(hbase + t0 + i * 64 + prow) * IDIM + lcol;
        boff[i] = (unsigned)(n0 + i * 64 + prow) * IDIM + lcol;
    }
    const int dst = tid * 16;

#define SG_AH0(b, t) do { unsigned k0_ = (unsigned)((t) & 63) * 64;       \
    gload16(Ah + aoff[0] + k0_, lds + (b) * 32768 + dst);                 \
    gload16(Ah + aoff[1] + k0_, lds + (b) * 32768 + 8192 + dst); } while (0)
#define SG_AH1(b, t) do { unsigned k0_ = (unsigned)((t) & 63) * 64;       \
    gload16(Ah + aoff[2] + k0_, lds + (b) * 32768 + 16384 + dst);         \
    gload16(Ah + aoff[3] + k0_, lds + (b) * 32768 + 24576 + dst); } while (0)
#define SG_BH0(b, t) do { unsigned k0_ = (unsigned)((t) & 63) * 64;       \
    gload16(B + boff[0] + k0_, lds + 65536 + (b) * 32768 + dst);          \
    gload16(B + boff[1] + k0_, lds + 65536 + (b) * 32768 + 8192 + dst); } while (0)
#define SG_BH1(b, t) do { unsigned k0_ = (unsigned)((t) & 63) * 64;       \
    gload16(B + boff[2] + k0_, lds + 65536 + (b) * 32768 + 16384 + dst);  \
    gload16(B + boff[3] + k0_, lds + 65536 + (b) * 32768 + 24576 + dst); } while (0)

    const int frd = (lane & 7) << 4;
    const int cb0 = (((lane >> 4) * 16)     ) ^ frd;
    const int cb1 = (((lane >> 4) * 16) | 64) ^ frd;
    const int arow = (wr * 64 + (lane & 15)) * 128;
    const int brow = (wc * 64 + (lane & 15)) * 128;

    f32x4 acc[8][4];
#pragma unroll
    for (int mi = 0; mi < 8; ++mi)
#pragma unroll
        for (int ni = 0; ni < 4; ++ni) acc[mi][ni] = (f32x4){0.f, 0.f, 0.f, 0.f};

    SG_AH0(0, 0); SG_BH0(0, 0); SG_AH1(0, 0); SG_BH1(0, 0);
    SG_AH0(1, 1); SG_BH0(1, 1);
    VMW(4);
    BARRIER();

    bf16x8 a0[2][4], a1[2][4], b01[2][2], b23[2][2];
    {
        const char* la = lds + arow;
        const char* lb = lds + 65536 + brow;
#pragma unroll
        for (int mi = 0; mi < 4; ++mi) {
            a0[0][mi] = *(const bf16x8*)(la + mi * 2048 + cb0);
            a0[1][mi] = *(const bf16x8*)(la + mi * 2048 + cb1);
        }
#pragma unroll
        for (int ni = 0; ni < 2; ++ni) {
            b01[0][ni] = *(const bf16x8*)(lb + ni * 2048 + cb0);
            b01[1][ni] = *(const bf16x8*)(lb + ni * 2048 + cb1);
        }
    }

    const int NT = IDIM / 64;   // 64
    for (int kt = 0; kt < NT; ++kt) {
        const int b  = kt & 1;
        const int bn = b ^ 1;
        const char* la  = lds + b * 32768 + arow;
        const char* lb  = lds + 65536 + b * 32768 + brow;
        const char* lan = lds + bn * 32768 + arow;
        const char* lbn = lds + 65536 + bn * 32768 + brow;

        // P1: pre-read b23(b); stage AH1(kt+1); MFMA a0 x b01
#pragma unroll
        for (int ni = 0; ni < 2; ++ni) {
            b23[0][ni] = *(const bf16x8*)(lb + (ni + 2) * 2048 + cb0);
            b23[1][ni] = *(const bf16x8*)(lb + (ni + 2) * 2048 + cb1);
        }
        SG_AH1(bn, kt + 1);
        PRIO1();
#pragma unroll
        for (int ks = 0; ks < 2; ++ks)
#pragma unroll
            for (int mi = 0; mi < 4; ++mi)
#pragma unroll
                for (int ni = 0; ni < 2; ++ni)
                    acc[mi][ni] = __builtin_amdgcn_mfma_f32_16x16x32_bf16(a0[ks][mi], b01[ks][ni], acc[mi][ni], 0, 0, 0);
        PRIO0(); BARRIER();

        // P2: pre-read a1(b); stage BH1(kt+1); MFMA a0 x b23
#pragma unroll
        for (int mi = 0; mi < 4; ++mi) {
            a1[0][mi] = *(const bf16x8*)(la + 16384 + mi * 2048 + cb0);
            a1[1][mi] = *(const bf16x8*)(la + 16384 + mi * 2048 + cb1);
        }
        SG_BH1(bn, kt + 1);
        PRIO1();
#pragma unroll
        for (int ks = 0; ks < 2; ++ks)
#pragma unroll
            for (int mi = 0; mi < 4; ++mi)
#pragma unroll
                for (int ni = 0; ni < 2; ++ni)
                    acc[mi][ni + 2] = __builtin_amdgcn_mfma_f32_16x16x32_bf16(a0[ks][mi], b23[ks][ni], acc[mi][ni + 2], 0, 0, 0);
        PRIO0(); BARRIER();

        // P3: stage AH0(kt+2); MFMA a1 x b01
        SG_AH0(b, kt + 2);
        PRIO1();
#pragma unroll
        for (int ks = 0; ks < 2; ++ks)
#pragma unroll
            for (int mi = 0; mi < 4; ++mi)
#pragma unroll
                for (int ni = 0; ni < 2; ++ni)
                    acc[mi + 4][ni] = __builtin_amdgcn_mfma_f32_16x16x32_bf16(a1[ks][mi], b01[ks][ni], acc[mi + 4][ni], 0, 0, 0);
        PRIO0(); BARRIER();

        // P4: stage BH0(kt+2); VMW(4); BAR; pre-read next a0/b01(bn); MFMA a1 x b23
        SG_BH0(b, kt + 2);
        VMW(4);
        BARRIER();
#pragma unroll
        for (int mi = 0; mi < 4; ++mi) {
            a0[0][mi] = *(const bf16x8*)(lan + mi * 2048 + cb0);
            a0[1][mi] = *(const bf16x8*)(lan + mi * 2048 + cb1);
        }
#pragma unroll
        for (int ni = 0; ni < 2; ++ni) {
            b01[0][ni] = *(const bf16x8*)(lbn + ni * 2048 + cb0);
            b01[1][ni] = *(const bf16x8*)(lbn + ni * 2048 + cb1);
        }
        PRIO1();
#pragma unroll
        for (int ks = 0; ks < 2; ++ks)
#pragma unroll
            for (int mi = 0; mi < 4; ++mi)
#pragma unroll
                for (int ni = 0; ni < 2; ++ni)
                    acc[mi + 4][ni + 2] = __builtin_amdgcn_mfma_f32_16x16x32_bf16(a1[ks][mi], b23[ks][ni], acc[mi + 4][ni + 2], 0, 0, 0);
        PRIO0();
        BARRIER();
    }
    VMW(0);
#undef SG_AH0
#undef SG_AH1
#undef SG_BH0
#undef SG_BH1

#pragma unroll
    for (int mi = 0; mi < 8; ++mi) {
        int qr = mi >> 2, m = mi & 3;
#pragma unroll
        for (int j = 0; j < 4; ++j) {
            int g = t0 + qr * 128 + wr * 64 + m * 16 + ((lane >> 4) << 2) + j;
            if (g < cnt) {
                int ent = list[g];
                int tok = ent & 0xFFFF;
                int sl  = ent >> 16;
                float w = wgt[(size_t)tok * NEXP + e];
                float* o = outP + (size_t)sl * T_TOK * HDIM + (size_t)tok * HDIM;
#pragma unroll
                for (int ni = 0; ni < 4; ++ni) {
                    int col = n0 + wc * 64 + ni * 16 + (lane & 15);
                    o[col] = w * acc[mi][ni][j];
                }
            }
        }
    }
}

// ---------------- combine ----------------
__global__ __launch_bounds__(256) void combine_k(const float* __restrict__ p0,
                                                 const float* __restrict__ p1,
                                                 float* __restrict__ out, long n4) {
    long i      = (long)blockIdx.x * 256 + threadIdx.x;
    long stride = (long)gridDim.x * 256;
    const float4* a4 = (const float4*)p0;
    const float4* b4 = (const float4*)p1;
    float4* o4 = (float4*)out;
    for (long j = i; j < n4; j += stride) {
        float4 a = a4[j], b = b4[j];
        o4[j] = make_float4(a.x + b.x, a.y + b.y, a.z + b.z, a.w + b.w);
    }
}

extern "C" void kernel_launch(void* const* d_in, const int* in_sizes, int n_in,
                              void* d_out, int out_size, void* d_ws, size_t ws_size,
                              hipStream_t stream) {
    const float* hs  = (const float*)d_in[0];
    const float* rw  = (const float*)d_in[1];
    const float* ws  = (const float*)d_in[2];
    const float* w2s = (const float*)d_in[3];
    float* out = (float*)d_out;

    char* wsp = (char*)d_ws;
    unsigned short* hs_bf = (unsigned short*)(wsp);                 //  33,554,432
    unsigned short* w_bf  = (unsigned short*)(wsp + 33554432ULL);   // 268,435,456
    unsigned short* w2_bf = (unsigned short*)(wsp + 301989888ULL);  // 134,217,728
    unsigned short* h_bf  = (unsigned short*)(wsp + 436207616ULL);  // 150,994,944 (18432 x IDIM)
    float*          outP  = (float*)(wsp + 587202560ULL);           // 134,217,728
    float*          wgt   = (float*)(wsp + 721420288ULL);           //     262,144
    int*            counts = (int*)(wsp + 721682432ULL);
    int*            offs   = (int*)(wsp + 721682560ULL);
    int*            lists  = (int*)(wsp + 721682688ULL);            //     262,144
    int*            desc   = (int*)(wsp + 721944832ULL);            //         512
    int*            ntiles = (int*)(wsp + 721945344ULL);

    hipMemsetAsync(counts, 0, NEXP * sizeof(int), stream);
    cvt_k<<<4096, 256, 0, stream>>>(ws, w_bf, (long)NEXP * 2 * IDIM * HDIM / 4);
    cvt_k<<<4096, 256, 0, stream>>>(w2s, w2_bf, (long)NEXP * HDIM * IDIM / 4);
    router_k<<<(T_TOK * 64) / 256, 256, 0, stream>>>(hs, rw, wgt, counts, lists, hs_bf);
    plan_k<<<1, 64, 0, stream>>>(counts, offs, desc, ntiles);

    gemm1_k<<<dim3(IDIM / 128, MAXT), 512, 131072, stream>>>(
        hs_bf, w_bf, h_bf, lists, counts, offs, desc, ntiles);
    gemm2_k<<<dim3(HDIM / 256, MAXT), 512, 131072, stream>>>(
        h_bf, w2_bf, wgt, outP, lists, counts, offs, desc, ntiles);
    combine_k<<<2048, 256, 0, stream>>>(outP, outP + (size_t)T_TOK * HDIM, out,
                                        (long)T_TOK * HDIM / 4);
}